// Round 3
// baseline (434.552 us; speedup 1.0000x reference)
//
#include <hip/hip_runtime.h>
#include <hip/hip_bf16.h>

using int32x4 = __attribute__((ext_vector_type(4))) int;

#define BM 256
#define BN 256
#define BKB 128  // K-bytes per tile = 2 x mfma_i32_16x16x64_i8 deep

#define GATE(n) asm volatile("s_waitcnt vmcnt(" #n ")" ::: "memory")
#define LGKM(n) asm volatile("s_waitcnt lgkmcnt(" #n ")" ::: "memory")
#define SCHED0() __builtin_amdgcn_sched_barrier(0)
#define BAR() __builtin_amdgcn_s_barrier()

// ---------------------------------------------------------------------------
// async 16B global->LDS (wave-uniform LDS base + lane*16; global addr per-lane)
__device__ __forceinline__ void load_lds16(const void* g, void* l) {
    __builtin_amdgcn_global_load_lds(
        (const __attribute__((address_space(1))) unsigned int*)g,
        (__attribute__((address_space(3))) unsigned int*)l, 16, 0, 0);
}

// ---------------------------------------------------------------------------
// Fused prep: blocks [0,M) quantize activations to signed int8 (xq - a_zp)
// + per-row sums; blocks [M, M+WB) convert weights int32 -> int8 (w - 128).
__global__ __launch_bounds__(256) void prep(
    const float* __restrict__ x, const float* __restrict__ act_scale,
    const int* __restrict__ act_zp, char* __restrict__ xs,
    int* __restrict__ rowsum, int K, int M,
    const int4* __restrict__ wq, char4* __restrict__ wsq, long n4)
{
    if (blockIdx.x < (unsigned)M) {
        __shared__ int wsum[4];
        const int row = blockIdx.x;
        const float s = act_scale[0];
        const int zp = act_zp[0];
        const float4* __restrict__ xr = (const float4*)(x + (size_t)row * K);
        char4* __restrict__ xo = (char4*)(xs + (size_t)row * K);
        const int nv = K >> 2;
        int sum = 0;
        for (int i = threadIdx.x; i < nv; i += 256) {
            float4 v = xr[i];
            int q0 = min(max((int)rintf(v.x / s) + zp, 0), 255) - zp;
            int q1 = min(max((int)rintf(v.y / s) + zp, 0), 255) - zp;
            int q2 = min(max((int)rintf(v.z / s) + zp, 0), 255) - zp;
            int q3 = min(max((int)rintf(v.w / s) + zp, 0), 255) - zp;
            sum += q0 + q1 + q2 + q3;
            char4 c;
            c.x = (char)q0; c.y = (char)q1; c.z = (char)q2; c.w = (char)q3;
            xo[i] = c;
        }
        for (int off = 32; off > 0; off >>= 1) sum += __shfl_down(sum, off, 64);
        if ((threadIdx.x & 63) == 0) wsum[threadIdx.x >> 6] = sum;
        __syncthreads();
        if (threadIdx.x == 0) rowsum[row] = wsum[0] + wsum[1] + wsum[2] + wsum[3];
    } else {
        long i = (long)(blockIdx.x - M) * 256 + threadIdx.x;
        if (i >= n4) return;
        int4 v = wq[i];
        char4 c;
        c.x = (char)(v.x - 128); c.y = (char)(v.y - 128);
        c.z = (char)(v.z - 128); c.w = (char)(v.w - 128);
        wsq[i] = c;
    }
}

// ---------------------------------------------------------------------------
// int8 GEMM, 256x256 tile, 8 waves (2M x 4N), BK=128 B, template-exact phases.
//
// Phase p of tile T (dual barrier, reads/stages issued BEFORE head barrier so
// LDS latency hides under barrier skew + other waves' previous MFMA cluster):
//   { ds_read frag(p) [+ all B at p0]; issue 2 global_load_lds;
//     [p0: lgkmcnt(8) throttle]; sched_barrier; s_barrier;
//     lgkmcnt(0); sched_barrier; setprio(1); 16 MFMA; setprio(0);
//     [p1: G2 gate][p3: G1 gate]; s_barrier }
// Staging (2 loads/thread/phase): p0:T+1.A2  p1:T+1.A3  p2:T+2.B0  p3:T+2.B1
//   A units -> slot s^1 (dead after T-1 p3 lgkm), B units -> slot s (B region
//   dead after T p0 lgkm). Units: B0=B[0,128) B1=B[128,256)
//   A2=A[0,64)u[128,192) A3=A[64,128)u[192,256); 2 loads (16 rows/wave) each.
// Per-wave flight list (oldest first) is fully traced; in-order vmcnt:
//   G1 (p3 of T, covers tile T+1's B + A2):  GATE(6)  [peel: 2 at T=NT-2]
//      outstanding there: [T+1.A3(2), T+2.B(4)] stay in flight.
//   G2 (p1 of T, covers T.A3):               GATE(8)  [peel: 0 at T=NT-1]
// Prologue issues [T0.B(4), T0.A(4), T1.B(4)] then GATE(6)+barrier.
// Min prefetch depth 3 phases (~1800+ cy at target util > ~900 cy HBM miss).
// NT >= 2 required (K >= 256; here K=4096 -> NT=32).
//
// LDS swizzle (conflict-free ds_read_b128): physical 16B chunk (row, pc)
// holds logical k-chunk c = pc ^ (row & 7); staging pre-swizzles the per-lane
// GLOBAL source; readers XOR with (r&7).
__global__ __launch_bounds__(512, 2) void gemm_i8(
    const char* __restrict__ Aq, const char* __restrict__ Bq,
    const int* __restrict__ rowsum, const float* __restrict__ wscale,
    const int* __restrict__ wzp, const float* __restrict__ ascale,
    const float* __restrict__ bias, float* __restrict__ C,
    int M, int N, int K)
{
    __shared__ __align__(16) char As[2][BM * BKB];  // 2 x 32 KiB
    __shared__ __align__(16) char Bs[2][BN * BKB];  // 2 x 32 KiB

    const int tid = threadIdx.x;
    const int w   = tid >> 6;
    const int l   = tid & 63;

    // T1: bijective XCD swizzle (m204)
    const int nwg = gridDim.x;
    const int nbx = N / BN;
    const int orig = blockIdx.x;
    const int xcd = orig & 7;
    const int rest = orig >> 3;
    const int qq = nwg >> 3, rr = nwg & 7;
    const int wg = (xcd < rr ? xcd * (qq + 1) : rr * (qq + 1) + (xcd - rr) * qq)
                   + rest;
    const int n0 = (wg % nbx) * BN;
    const int m0 = (wg / nbx) * BM;

    const int wm = (w & 1) * 128;   // wave m-offset in tile
    const int wn = (w >> 1) * 64;   // wave n-offset in tile

    // ---- staging source (per-lane, pre-swizzled) + LDS unit bases ----
    const int lr8 = l >> 3;
    const int csw = (((l & 7) ^ (lr8 & 7)) << 4);
    const int rB0 = w * 16;
    const int rA2 = (w < 4) ? (w * 16) : (128 + (w - 4) * 16);

    const char* sB0 = Bq + (size_t)(n0 + rB0 + lr8) * K + csw;
    const char* sB1 = sB0 + (size_t)128 * K;
    const char* sA2 = Aq + (size_t)(m0 + rA2 + lr8) * K + csw;
    const char* sA3 = sA2 + (size_t)64 * K;
    const size_t k8 = (size_t)8 * K;

    const int oB0 = rB0 * BKB;
    const int oB1 = oB0 + 128 * BKB;
    const int oA2 = rA2 * BKB;
    const int oA3 = oA2 + 64 * BKB;

    // ---- fragment read offsets ----
    const int r   = l & 15;
    const int qk  = l >> 4;
    const int rx  = r & 7;
    const int rof = r * BKB;
    const int ck0 = ((qk ^ rx) << 4);
    const int ck1 = (((4 + qk) ^ rx) << 4);

    int32x4 acc[8][4] = {};
    const int NT = K / BKB;

    // prologue — flight order matches steady state: T0.B, T0.A, T1.B
    load_lds16(sB0,      Bs[0] + oB0);
    load_lds16(sB0 + k8, Bs[0] + oB0 + 1024);
    load_lds16(sB1,      Bs[0] + oB1);
    load_lds16(sB1 + k8, Bs[0] + oB1 + 1024);
    load_lds16(sA2,      As[0] + oA2);
    load_lds16(sA2 + k8, As[0] + oA2 + 1024);
    load_lds16(sA3,      As[0] + oA3);
    load_lds16(sA3 + k8, As[0] + oA3 + 1024);
    if (NT > 1) {
        load_lds16(sB0 + BKB,      Bs[1] + oB0);
        load_lds16(sB0 + BKB + k8, Bs[1] + oB0 + 1024);
        load_lds16(sB1 + BKB,      Bs[1] + oB1);
        load_lds16(sB1 + BKB + k8, Bs[1] + oB1 + 1024);
    }
    sA2 += BKB; sA3 += BKB;                           // next A issue: tile 1
    sB0 += 2 * (size_t)BKB; sB1 += 2 * (size_t)BKB;   // next B issue: tile 2

    GATE(6);   // land T0.B + T0.A2 (leaves T0.A3, T1.B in flight)
    BAR();

#define READ_A(p)                                                       \
    { const char* ab = cA + (wm + (p) * 32) * BKB + rof;                \
      af[0][0] = *(const int32x4*)(ab + ck0);                           \
      af[0][1] = *(const int32x4*)(ab + ck1);                           \
      af[1][0] = *(const int32x4*)(ab + 2048 + ck0);                    \
      af[1][1] = *(const int32x4*)(ab + 2048 + ck1); }

#define CLUSTER(p)                                                      \
    __builtin_amdgcn_s_setprio(1);                                      \
    _Pragma("unroll")                                                   \
    for (int i = 0; i < 2; ++i)                                         \
        _Pragma("unroll")                                               \
        for (int j = 0; j < 4; ++j) {                                   \
            acc[(p)*2+i][j] = __builtin_amdgcn_mfma_i32_16x16x64_i8(    \
                af[i][0], bf[j][0], acc[(p)*2+i][j], 0, 0, 0);          \
            acc[(p)*2+i][j] = __builtin_amdgcn_mfma_i32_16x16x64_i8(    \
                af[i][1], bf[j][1], acc[(p)*2+i][j], 0, 0, 0);          \
        }                                                               \
    __builtin_amdgcn_s_setprio(0);

#define HEAD() SCHED0(); BAR(); LGKM(0); SCHED0()

    int s = 0;
    for (int T = 0; T < NT; ++T) {
        const char* cA = As[s];
        const char* cB = Bs[s];
        char* nA = As[s ^ 1];   // tile T+1's A
        char* nB = Bs[s];       // tile T+2's B (same parity as T)
        const bool stA = (T + 1 < NT);
        const bool stB = (T + 2 < NT);
        int32x4 af[2][2], bf[4][2];

        // ---------------- phase 0 ----------------
        READ_A(0);
        { const char* bb = cB + wn * BKB + rof;
#pragma unroll
          for (int j = 0; j < 4; ++j) {
              bf[j][0] = *(const int32x4*)(bb + j * 2048 + ck0);
              bf[j][1] = *(const int32x4*)(bb + j * 2048 + ck1);
          } }
        if (stA) { load_lds16(sA2,      nA + oA2);
                   load_lds16(sA2 + k8, nA + oA2 + 1024); }
        LGKM(8);     // throttle: 12 ds_reads issued this phase
        HEAD();
        CLUSTER(0);
        BAR();
        // ---------------- phase 1 ----------------
        READ_A(1);
        if (stA) { load_lds16(sA3,      nA + oA3);
                   load_lds16(sA3 + k8, nA + oA3 + 1024); }
        HEAD();
        CLUSTER(1);
        if (stA) { GATE(8); } else { GATE(0); }   // G2: land T.A3
        BAR();
        // ---------------- phase 2 ----------------
        READ_A(2);
        if (stB) { load_lds16(sB0,      nB + oB0);
                   load_lds16(sB0 + k8, nB + oB0 + 1024); }
        HEAD();
        CLUSTER(2);
        BAR();
        // ---------------- phase 3 ----------------
        READ_A(3);
        if (stB) { load_lds16(sB1,      nB + oB1);
                   load_lds16(sB1 + k8, nB + oB1 + 1024); }
        HEAD();
        CLUSTER(3);
        if (stB) { GATE(6); }                     // G1: land T+1.B + T+1.A2
        else if (stA) { GATE(2); }                // peel at T = NT-2
        BAR();

        sA2 += BKB; sA3 += BKB; sB0 += BKB; sB1 += BKB;
        s ^= 1;
    }

    // epilogue: C/D layout col=lane&15, row=(lane>>4)*4+reg.
    // mkscales fused: alpha = a_s*w_s[n], beta = alpha*(128 - w_zp[n]).
    const float as = ascale[0];
    const int r4  = qk * 4;
    const int cil = r;
#pragma unroll
    for (int j = 0; j < 4; ++j) {
        const int col = n0 + wn + j * 16 + cil;
        const float al = as * wscale[col];
        const float be = al * (float)(128 - wzp[col]);
        const float bi = bias[col];
#pragma unroll
        for (int mi = 0; mi < 8; ++mi) {
            const int rowb = m0 + wm + mi * 16 + r4;
#pragma unroll
            for (int t = 0; t < 4; ++t) {
                const int row = rowb + t;
                C[(size_t)row * N + col] =
                    al * (float)acc[mi][j][t] + be * (float)rowsum[row] + bi;
            }
        }
    }
}

// ---------------------------------------------------------------------------
extern "C" void kernel_launch(void* const* d_in, const int* in_sizes, int n_in,
                              void* d_out, int out_size, void* d_ws, size_t ws_size,
                              hipStream_t stream) {
    const float* x      = (const float*)d_in[0];
    const int*   wq     = (const int*)d_in[1];
    const float* wscale = (const float*)d_in[2];
    const int*   wzp    = (const int*)d_in[3];
    const float* ascale = (const float*)d_in[4];
    const int*   azp    = (const int*)d_in[5];
    const float* bias   = (const float*)d_in[6];
    float* out = (float*)d_out;

    const int N = in_sizes[2];          // OUT
    const int K = in_sizes[1] / N;      // IN
    const int M = in_sizes[0] / K;      // B*S

    char* ws     = (char*)d_ws;
    char* xs     = ws;                                 // M*K int8
    char* wsq    = ws + (size_t)M * K;                 // N*K int8
    int*  rowsum = (int*)(wsq + (size_t)N * K);        // M int32

    long n4 = (long)N * K / 4;
    int wblocks = (int)((n4 + 255) / 256);
    prep<<<M + wblocks, 256, 0, stream>>>(
        x, ascale, azp, xs, rowsum, K, M, (const int4*)wq, (char4*)wsq, n4);

    dim3 grid((M / BM) * (N / BN));
    gemm_i8<<<grid, 512, 0, stream>>>(
        xs, wsq, rowsum, wscale, wzp, ascale, bias, out, M, N, K);
}